// Round 1
// 382.600 us; speedup vs baseline: 1.1006x; 1.1006x over previous
//
#include <hip/hip_runtime.h>
#include <hip/hip_bf16.h>

#define F 128          // feature dim
#define F4 32          // feature dim in 4-element quads
#define CH 8192        // edges per coarse-scatter block

typedef __attribute__((ext_vector_type(8))) short bf16x8;
typedef __attribute__((ext_vector_type(4))) float f32x4;
typedef __attribute__((ext_vector_type(2))) float f32x2;

static __device__ inline unsigned short f2bf(float f) {
    __hip_bfloat16 b = __float2bfloat16(f);
    return *(unsigned short*)&b;
}

// decode 4 packed fp8-e4m3 bytes -> 4 floats (HW cvt)
__device__ inline float4 fp8x4_to_f4(int w) {
    f32x2 lo = __builtin_amdgcn_cvt_pk_f32_fp8(w, false);
    f32x2 hi = __builtin_amdgcn_cvt_pk_f32_fp8(w, true);
    float4 f;
    f.x = lo[0]; f.y = lo[1]; f.z = hi[0]; f.w = hi[1];
    return f;
}

// encode 1 float -> fp8-e4m3 byte (HW cvt)
__device__ inline unsigned char f_to_fp8(float a) {
    int p = __builtin_amdgcn_cvt_pk_fp8_f32(a, a, 0, false);
    return (unsigned char)(p & 0xFF);
}

// pack 4 floats -> 4 fp8 bytes
__device__ inline int f4_to_fp8x4(float4 a) {
    int w = __builtin_amdgcn_cvt_pk_fp8_f32(a.x, a.y, 0, false);
    w = __builtin_amdgcn_cvt_pk_fp8_f32(a.z, a.w, w, true);
    return w;
}

// ============ CSR build via bucketed counting sort ============
// Replaces the 1.6M device-scope atomicAdd histogram (25 G/s floor, 63.5 us)
// + random-scatter k_place with: LDS histograms + ~150k global atomics total.

// P1: coarse global histogram, bucket = dst >> 8 (256 nodes/bucket)
__global__ void k_bhist(const int* __restrict__ dst, int* __restrict__ ghist,
                        int e, int nbuk) {
    __shared__ int h[512];
    for (int t = threadIdx.x; t < nbuk; t += 256) h[t] = 0;
    __syncthreads();
    int stride = gridDim.x * blockDim.x;
    for (int i = blockIdx.x * blockDim.x + threadIdx.x; i < e; i += stride)
        atomicAdd(&h[dst[i] >> 8], 1);
    __syncthreads();
    for (int t = threadIdx.x; t < nbuk; t += 256)
        if (h[t]) atomicAdd(&ghist[t], h[t]);
}

// P2: exclusive scan of bucket counts (nbuk <= 512), writes gbase[0..nbuk]
// (gbase[nbuk] = e) and initializes the reservation cursors.
__global__ void k_bscan(const int* __restrict__ ghist, int* __restrict__ gbase,
                        int* __restrict__ cursor, int nbuk) {
    __shared__ int s[512];
    int t = threadIdx.x;
    int v = (t < nbuk) ? ghist[t] : 0;
    s[t] = v;
    __syncthreads();
    for (int off = 1; off < 512; off <<= 1) {
        int u = (t >= off) ? s[t - off] : 0;
        __syncthreads();
        s[t] += u;
        __syncthreads();
    }
    if (t < nbuk) {
        int ex = s[t] - v;
        gbase[t] = ex;
        cursor[t] = ex;
        if (t == nbuk - 1) gbase[nbuk] = s[t];
    }
}

// P3: scatter (dst,src) pairs into contiguous bucket chunks.
// One global atomic per (block,bucket) reserves space; LDS atomics assign slots.
__global__ void k_bscatter(const int* __restrict__ src, const int* __restrict__ dst,
                           int* __restrict__ cursor, int2* __restrict__ coarse,
                           int e, int nbuk) {
    __shared__ int h[512];
    __shared__ int base[512];
    for (int t = threadIdx.x; t < nbuk; t += 256) h[t] = 0;
    __syncthreads();
    int beg = blockIdx.x * CH;
    int end = beg + CH; if (end > e) end = e;
    for (int i = beg + threadIdx.x; i < end; i += 256)
        atomicAdd(&h[dst[i] >> 8], 1);
    __syncthreads();
    for (int t = threadIdx.x; t < nbuk; t += 256) {
        int c = h[t];
        base[t] = c ? atomicAdd(&cursor[t], c) : 0;
        h[t] = 0;                    // reuse as block-local cursor
    }
    __syncthreads();
    for (int i = beg + threadIdx.x; i < end; i += 256) {
        int d = dst[i];
        int b = d >> 8;
        int p = atomicAdd(&h[b], 1);
        coarse[base[b] + p] = make_int2(d, src[i]);
    }
}

// P4: one block per bucket. Exact per-node counts -> rowptr + dinv, then
// final in-bucket scatter of src into col (writes stay within a ~16KB chunk).
__global__ void k_bfine(const int2* __restrict__ coarse, const int* __restrict__ gbase,
                        int* __restrict__ rowptr, float* __restrict__ dinv,
                        int* __restrict__ col, int n, int e) {
    __shared__ int h[256];
    __shared__ int sb[256];
    int b = blockIdx.x;
    int t = threadIdx.x;
    h[t] = 0;
    __syncthreads();
    int beg = gbase[b], end = gbase[b + 1];
    for (int i = beg + t; i < end; i += 256)
        atomicAdd(&h[coarse[i].x & 255], 1);
    __syncthreads();
    int cnt = h[t];
    sb[t] = cnt;
    __syncthreads();
    for (int off = 1; off < 256; off <<= 1) {
        int u = (t >= off) ? sb[t - off] : 0;
        __syncthreads();
        sb[t] += u;
        __syncthreads();
    }
    int ex = sb[t] - cnt;            // exclusive scan (local base within bucket)
    int v = b * 256 + t;
    if (v < n) {
        rowptr[v] = beg + ex;
        dinv[v] = 1.0f / sqrtf((float)cnt + 1.0f);
    }
    h[t] = ex;                       // reuse as per-node cursor
    __syncthreads();
    for (int i = beg + t; i < end; i += 256) {
        int2 p = coarse[i];
        int q = atomicAdd(&h[p.x & 255], 1);
        col[beg + q] = p.y;
    }
    if (b == 0 && t == 0) rowptr[n] = e;
}

// ---------- pack all 3 W (fp32 128x128) into MFMA B-fragment order, bf16 ----------
__global__ void k_packW3(const float* __restrict__ W1, const float* __restrict__ W2,
                         const float* __restrict__ W3, unsigned short* __restrict__ Wp) {
    int gb = blockIdx.x;                        // 0..191
    const float* W = (gb < 64) ? W1 : ((gb < 128) ? W2 : W3);
    unsigned short* out = Wp + (size_t)(gb >> 6) * 16384;
    int idx = (gb & 63) * 256 + threadIdx.x;    // 0..16383
    int i    = idx & 7;
    int lane = (idx >> 3) & 63;
    int kk   = (idx >> 9) & 3;
    int ct   = idx >> 11;
    int k = kk * 32 + ((lane >> 4) * 8) + i;
    int c = ct * 16 + (lane & 15);
    out[idx] = f2bf(W[k * F + c]);
}

// ---------- MFMA matmul: Wp in LDS; 128 rows/block; epilogue scales by dinv ----------
// H8s[row] = fp8( (X@W)[row] * dinv[row] )  — dinv folded here so the aggregate
// needs no per-edge dinv gathers.
#define MM2_PROLOG                                                                  \
    __shared__ unsigned short wlds[16384];                                          \
    {                                                                               \
        const uint4* wsrc = (const uint4*)Wp;                                       \
        uint4* wdst = (uint4*)wlds;                                                 \
        _Pragma("unroll")                                                           \
        for (int i = 0; i < 8; ++i)                                                 \
            wdst[threadIdx.x + 256 * i] = wsrc[threadIdx.x + 256 * i];              \
    }                                                                               \
    __syncthreads();                                                                \
    int wave = threadIdx.x >> 6;                                                    \
    int lane = threadIdx.x & 63;                                                    \
    int row0 = blockIdx.x * 128 + wave * 32;                                        \
    if (row0 >= n) return;                                                          \
    int arowA = row0 + (lane & 15);                                                 \
    int arowB = arowA + 16;                                                         \
    if (arowA >= n) arowA = n - 1;                                                  \
    if (arowB >= n) arowB = n - 1;

#define MM2_TAIL                                                                    \
    int orow0 = row0 + ((lane >> 4) * 4);                                           \
    int colc = lane & 15;                                                           \
    float dvA[4], dvB[4];                                                           \
    _Pragma("unroll")                                                               \
    for (int r = 0; r < 4; ++r) {                                                   \
        int ra = orow0 + r, rb = ra + 16;                                           \
        dvA[r] = dinv[ra < n ? ra : n - 1];                                         \
        dvB[r] = dinv[rb < n ? rb : n - 1];                                         \
    }                                                                               \
    _Pragma("unroll")                                                               \
    for (int ct = 0; ct < 8; ++ct) {                                                \
        _Pragma("unroll")                                                           \
        for (int r = 0; r < 4; ++r) {                                               \
            int rowA = orow0 + r;                                                   \
            int rowB = rowA + 16;                                                   \
            if (rowA < n) H[(size_t)rowA * F + ct * 16 + colc] = f_to_fp8(accA[ct][r] * dvA[r]); \
            if (rowB < n) H[(size_t)rowB * F + ct * 16 + colc] = f_to_fp8(accB[ct][r] * dvB[r]); \
        }                                                                           \
    }

#define MM2_CORE(LOADA, LOADB)                                                      \
    f32x4 accA[8], accB[8];                                                         \
    _Pragma("unroll")                                                               \
    for (int ct = 0; ct < 8; ++ct) {                                                \
        accA[ct] = (f32x4){0.f, 0.f, 0.f, 0.f};                                     \
        accB[ct] = (f32x4){0.f, 0.f, 0.f, 0.f};                                     \
    }                                                                               \
    _Pragma("unroll")                                                               \
    for (int kk = 0; kk < 4; ++kk) {                                                \
        bf16x8 aA = LOADA(kk);                                                      \
        bf16x8 aB = LOADB(kk);                                                      \
        _Pragma("unroll")                                                           \
        for (int ct = 0; ct < 8; ++ct) {                                            \
            bf16x8 b = *(const bf16x8*)(wlds + ((size_t)(ct * 4 + kk) * 64 + lane) * 8); \
            accA[ct] = __builtin_amdgcn_mfma_f32_16x16x32_bf16(aA, b, accA[ct], 0, 0, 0); \
            accB[ct] = __builtin_amdgcn_mfma_f32_16x16x32_bf16(aB, b, accB[ct], 0, 0, 0); \
        }                                                                           \
    }

// fp32-input variant (layer 1)
__global__ __launch_bounds__(256, 2)
void k_mm_f32(const float* __restrict__ Xf,
              const unsigned short* __restrict__ Wp,
              const float* __restrict__ dinv,
              unsigned char* __restrict__ H, int n) {
    MM2_PROLOG
    const float* AbA = Xf + (size_t)arowA * F + ((lane >> 4) * 8);
    const float* AbB = Xf + (size_t)arowB * F + ((lane >> 4) * 8);
#define LA_F32(kk) ({                                               \
        float4 a0 = *(const float4*)(AbA + (kk) * 32);              \
        float4 a1 = *(const float4*)(AbA + (kk) * 32 + 4);          \
        bf16x8 av;                                                  \
        av[0] = (short)f2bf(a0.x); av[1] = (short)f2bf(a0.y);       \
        av[2] = (short)f2bf(a0.z); av[3] = (short)f2bf(a0.w);       \
        av[4] = (short)f2bf(a1.x); av[5] = (short)f2bf(a1.y);       \
        av[6] = (short)f2bf(a1.z); av[7] = (short)f2bf(a1.w);       \
        av; })
#define LB_F32(kk) ({                                               \
        float4 a0 = *(const float4*)(AbB + (kk) * 32);              \
        float4 a1 = *(const float4*)(AbB + (kk) * 32 + 4);          \
        bf16x8 av;                                                  \
        av[0] = (short)f2bf(a0.x); av[1] = (short)f2bf(a0.y);       \
        av[2] = (short)f2bf(a0.z); av[3] = (short)f2bf(a0.w);       \
        av[4] = (short)f2bf(a1.x); av[5] = (short)f2bf(a1.y);       \
        av[6] = (short)f2bf(a1.z); av[7] = (short)f2bf(a1.w);       \
        av; })
    MM2_CORE(LA_F32, LB_F32)
#undef LA_F32
#undef LB_F32
    MM2_TAIL
}

// fp8-input variant (layers 2,3): activations stored fp8, cvt to bf16 in-register
__global__ __launch_bounds__(256, 2)
void k_mm_fp8(const unsigned char* __restrict__ X8,
              const unsigned short* __restrict__ Wp,
              const float* __restrict__ dinv,
              unsigned char* __restrict__ H, int n) {
    MM2_PROLOG
    const unsigned char* AbA = X8 + (size_t)arowA * F + ((lane >> 4) * 8);
    const unsigned char* AbB = X8 + (size_t)arowB * F + ((lane >> 4) * 8);
#define LA_FP8(kk) ({                                               \
        uint2 u = *(const uint2*)(AbA + (kk) * 32);                 \
        float4 lo = fp8x4_to_f4((int)u.x);                          \
        float4 hi = fp8x4_to_f4((int)u.y);                          \
        bf16x8 av;                                                  \
        av[0] = (short)f2bf(lo.x); av[1] = (short)f2bf(lo.y);       \
        av[2] = (short)f2bf(lo.z); av[3] = (short)f2bf(lo.w);       \
        av[4] = (short)f2bf(hi.x); av[5] = (short)f2bf(hi.y);       \
        av[6] = (short)f2bf(hi.z); av[7] = (short)f2bf(hi.w);       \
        av; })
#define LB_FP8(kk) ({                                               \
        uint2 u = *(const uint2*)(AbB + (kk) * 32);                 \
        float4 lo = fp8x4_to_f4((int)u.x);                          \
        float4 hi = fp8x4_to_f4((int)u.y);                          \
        bf16x8 av;                                                  \
        av[0] = (short)f2bf(lo.x); av[1] = (short)f2bf(lo.y);       \
        av[2] = (short)f2bf(lo.z); av[3] = (short)f2bf(lo.w);       \
        av[4] = (short)f2bf(hi.x); av[5] = (short)f2bf(hi.y);       \
        av[6] = (short)f2bf(hi.z); av[7] = (short)f2bf(hi.w);       \
        av; })
    MM2_CORE(LA_FP8, LB_FP8)
#undef LA_FP8
#undef LB_FP8
    MM2_TAIL
}

// ---------- aggregate: out = relu(dv * (sum H8s[s] + H8s[v]) + b) ----------
// H8s already carries dinv[src]; per-edge work = col load + row gather + 4 adds.
#define AGG_EDGE(s_) {                                                               \
        float4 h_ = fp8x4_to_f4(H8[(size_t)(s_) * F4 + lane]);                       \
        acc.x += h_.x; acc.y += h_.y; acc.z += h_.z; acc.w += h_.w; }

#define AGG_BODY                                                                     \
    float dv = dinv[v];                                                              \
    float4 acc = fp8x4_to_f4(H8[(size_t)v * F4 + lane]);  /* selfloop term */        \
    int beg = rowptr[v], end = rowptr[v + 1];                                        \
    int j = beg;                                                                     \
    for (; j + 7 < end; j += 8) {                                                    \
        int s0 = col[j], s1 = col[j+1], s2 = col[j+2], s3 = col[j+3];                \
        int s4 = col[j+4], s5 = col[j+5], s6 = col[j+6], s7 = col[j+7];              \
        int q0 = H8[(size_t)s0*F4+lane], q1 = H8[(size_t)s1*F4+lane];                \
        int q2 = H8[(size_t)s2*F4+lane], q3 = H8[(size_t)s3*F4+lane];                \
        int q4 = H8[(size_t)s4*F4+lane], q5 = H8[(size_t)s5*F4+lane];                \
        int q6 = H8[(size_t)s6*F4+lane], q7 = H8[(size_t)s7*F4+lane];                \
        float4 h0 = fp8x4_to_f4(q0), h1 = fp8x4_to_f4(q1);                           \
        float4 h2 = fp8x4_to_f4(q2), h3 = fp8x4_to_f4(q3);                           \
        float4 h4 = fp8x4_to_f4(q4), h5 = fp8x4_to_f4(q5);                           \
        float4 h6 = fp8x4_to_f4(q6), h7 = fp8x4_to_f4(q7);                           \
        acc.x += h0.x + h1.x; acc.y += h0.y + h1.y;                                  \
        acc.z += h0.z + h1.z; acc.w += h0.w + h1.w;                                  \
        acc.x += h2.x + h3.x; acc.y += h2.y + h3.y;                                  \
        acc.z += h2.z + h3.z; acc.w += h2.w + h3.w;                                  \
        acc.x += h4.x + h5.x; acc.y += h4.y + h5.y;                                  \
        acc.z += h4.z + h5.z; acc.w += h4.w + h5.w;                                  \
        acc.x += h6.x + h7.x; acc.y += h6.y + h7.y;                                  \
        acc.z += h6.z + h7.z; acc.w += h6.w + h7.w;                                  \
    }                                                                                \
    for (; j + 3 < end; j += 4) {                                                    \
        int s0 = col[j], s1 = col[j+1], s2 = col[j+2], s3 = col[j+3];                \
        AGG_EDGE(s0) AGG_EDGE(s1) AGG_EDGE(s2) AGG_EDGE(s3)                          \
    }                                                                                \
    for (; j < end; ++j) { AGG_EDGE(col[j]) }                                        \
    float4 bb = b4[lane];                                                            \
    acc.x = fmaxf(fmaf(acc.x, dv, bb.x), 0.f);                                       \
    acc.y = fmaxf(fmaf(acc.y, dv, bb.y), 0.f);                                       \
    acc.z = fmaxf(fmaf(acc.z, dv, bb.z), 0.f);                                       \
    acc.w = fmaxf(fmaf(acc.w, dv, bb.w), 0.f);

// layers 1-2: write fp8 activations
__global__ void k_aggregate(const int* __restrict__ H8,
                            const int* __restrict__ rowptr,
                            const int* __restrict__ col,
                            const float* __restrict__ dinv,
                            const float4* __restrict__ b4,
                            int* __restrict__ out8, int n) {
    int v = blockIdx.x * 8 + (threadIdx.x >> 5);
    int lane = threadIdx.x & 31;
    if (v >= n) return;
    AGG_BODY
    out8[(size_t)v * F4 + lane] = f4_to_fp8x4(acc);
}

// layer 3: per-block partials -> coalesced scratch (NO atomics into pooled —
// 1.6M atomics into pooled[128] was the R9 1210µs cross-XCD line-bounce bug)
__global__ void k_aggregate_pool(const int* __restrict__ H8,
                                 const int* __restrict__ rowptr,
                                 const int* __restrict__ col,
                                 const float* __restrict__ dinv,
                                 const float4* __restrict__ b4,
                                 float4* __restrict__ part, int n) {
    int v = blockIdx.x * 8 + (threadIdx.x >> 5);
    int lane = threadIdx.x & 31;
    float4 res = {0.f, 0.f, 0.f, 0.f};
    if (v < n) {
        AGG_BODY
        res = acc;
    }
    __shared__ float4 sm[256];
    sm[threadIdx.x] = res;
    __syncthreads();
    if (threadIdx.x < 32) {
        float4 a = sm[threadIdx.x];
        for (int g = 1; g < 8; ++g) {
            float4 o = sm[g * 32 + threadIdx.x];
            a.x += o.x; a.y += o.y; a.z += o.z; a.w += o.w;
        }
        part[(size_t)blockIdx.x * 32 + threadIdx.x] = a;   // coalesced 512 B/block
    }
}

// ---------- fold block partials into pooled (16k atomics total: safe) ----------
__global__ void k_reduce_pool(const float* __restrict__ part, float* pooled,
                              int nb, float inv_n) {
    int f = threadIdx.x & (F - 1);
    int half = threadIdx.x >> 7;   // 0 or 1
    float s = 0.f;
    for (int r = blockIdx.x * 2 + half; r < nb; r += gridDim.x * 2)
        s += part[(size_t)r * F + f];
    __shared__ float sm[256];
    sm[threadIdx.x] = s;
    __syncthreads();
    if (threadIdx.x < F)
        atomicAdd(&pooled[f], (sm[threadIdx.x] + sm[threadIdx.x + F]) * inv_n);
}

// ---------- final FC ----------
__global__ void k_fc(const float* __restrict__ pooled, const float* __restrict__ fcw,
                     const float* __restrict__ fcb, float* out) {
    __shared__ float sm[2 * F];
    int f = threadIdx.x;
    float p = pooled[f];
    sm[f]     = p * fcw[f * 2 + 0];
    sm[f + F] = p * fcw[f * 2 + 1];
    __syncthreads();
    for (int off = 64; off > 0; off >>= 1) {
        if (f < off) {
            sm[f]     += sm[f + off];
            sm[F + f] += sm[F + f + off];
        }
        __syncthreads();
    }
    if (f == 0) {
        out[0] = sm[0] + fcb[0];
        out[1] = sm[F] + fcb[1];
    }
}

extern "C" void kernel_launch(void* const* d_in, const int* in_sizes, int n_in,
                              void* d_out, int out_size, void* d_ws, size_t ws_size,
                              hipStream_t stream) {
    const float* x   = (const float*)d_in[0];
    const int*   ei  = (const int*)  d_in[1];
    const float* W1  = (const float*)d_in[2];
    const float* b1  = (const float*)d_in[3];
    const float* W2  = (const float*)d_in[4];
    const float* b2  = (const float*)d_in[5];
    const float* W3  = (const float*)d_in[6];
    const float* b3  = (const float*)d_in[7];
    const float* fcw = (const float*)d_in[8];
    const float* fcb = (const float*)d_in[9];
    float* out = (float*)d_out;

    const int n = in_sizes[0] / F;     // 100000
    const int e = in_sizes[1] / 2;     // 1600000
    const int* src = ei;
    const int* dst = ei + e;

    const int BT = 256;
    dim3 blk(BT);
    int gAgg  = (n + 7) / 8;           // 12500
    int gMM   = (n + 127) / 128;       // 782
    int nbuk  = (n + 255) >> 8;        // 391 coarse buckets (256 nodes each)
    int gSc   = (e + CH - 1) / CH;     // 196 coarse-scatter blocks

    // workspace layout (16B-aligned chunks)
    float* ws     = (float*)d_ws;
    float* dinv   = ws;                          // n
    float* pooled = dinv + n;                    // 128
    int*   rowptr = (int*)(pooled + 128);        // n+4
    int*   ghist  = rowptr + (n + 4);            // 512
    int*   gbase  = ghist + 512;                 // 512 (nbuk+1 used)
    int*   cursor = gbase + 512;                 // 512
    int*   col    = cursor + 512;                // e
    unsigned short* Wp = (unsigned short*)(col + e);    // 3*16384
    float* part = (float*)(Wp + 3 * 16384);             // gAgg*128 fp32 partials
    unsigned char* Ab = (unsigned char*)(part + (size_t)gAgg * F);  // n*F fp8
    unsigned char* Bb = Ab + (size_t)n * F;                         // n*F fp8
    unsigned char* H8 = Bb + (size_t)n * F;                         // n*F fp8
    // coarse (dst,src) pairs: e*8 B, aliases Ab..Bb (25.6 MB). Safe: Ab/Bb are
    // first written by the layer aggregates, which run strictly after k_bfine
    // has consumed coarse (same stream).
    int2* coarse = (int2*)Ab;

    // ---- CSR build: bucketed counting sort (no per-edge global atomics) ----
    hipMemsetAsync(ghist, 0, 512 * sizeof(int), stream);
    hipMemsetAsync(pooled, 0, F * sizeof(float), stream);
    k_bhist   <<<256, blk, 0, stream>>>(dst, ghist, e, nbuk);
    k_bscan   <<<1, dim3(512), 0, stream>>>(ghist, gbase, cursor, nbuk);
    k_bscatter<<<gSc, blk, 0, stream>>>(src, dst, cursor, coarse, e, nbuk);
    k_bfine   <<<nbuk, blk, 0, stream>>>(coarse, gbase, rowptr, dinv, col, n, e);

    // ---- weight packing ----
    k_packW3<<<192, blk, 0, stream>>>(W1, W2, W3, Wp);

    // ---- 3 GCN layers: X @ W (·dinv) -> fp8 H8s -> gather-sum ·dv -> fp8 act ----
    // layer 1 (fp32 input)
    k_mm_f32<<<gMM, blk, 0, stream>>>(x, Wp, dinv, H8, n);
    k_aggregate<<<gAgg, blk, 0, stream>>>((const int*)H8, rowptr, col, dinv,
                                          (const float4*)b1, (int*)Ab, n);
    // layer 2
    k_mm_fp8<<<gMM, blk, 0, stream>>>(Ab, Wp + 16384, dinv, H8, n);
    k_aggregate<<<gAgg, blk, 0, stream>>>((const int*)H8, rowptr, col, dinv,
                                          (const float4*)b2, (int*)Bb, n);
    // layer 3: aggregate fused with pooling via coalesced per-block partials
    k_mm_fp8<<<gMM, blk, 0, stream>>>(Bb, Wp + 2 * 16384, dinv, H8, n);
    k_aggregate_pool<<<gAgg, blk, 0, stream>>>((const int*)H8, rowptr, col, dinv,
                                               (const float4*)b3, (float4*)part, n);
    k_reduce_pool<<<128, blk, 0, stream>>>(part, pooled, gAgg, 1.0f / (float)n);

    // ---- FC ----
    k_fc<<<1, dim3(F), 0, stream>>>(pooled, fcw, fcb, out);
}